// Round 1
// baseline (96.410 us; speedup 1.0000x reference)
//
#include <hip/hip_runtime.h>
#include <math.h>

// Problem constants (from reference): B=8, C=32, F=32, K=3, H=W=32
#define NB 8
#define NC 32
#define NF 32
#define NH 32
#define NW 32
#define NQ 9
#define TS 34            // padded tile stride (H+2)
#define TILE_N (TS * TS) // 1156

// Block = 256 threads, each owns 2 vertically-adjacent output pixels.
// Grid = B*F*2 (512): one block per (b, f, image-half) -> 2 blocks/CU.
// Coefficients are block-uniform -> scalar loads (SGPRs), no per-lane cost.
__global__ __launch_bounds__(256) void ka_conv_rational_kernel(
    const float* __restrict__ x,     // [B, C, H, W]
    const float* __restrict__ nums,  // [F*Q*C, 6]
    const float* __restrict__ dens,  // [F*Q*C, 4]
    float* __restrict__ out)         // [B, F, H, W]
{
    __shared__ float tile[2][TILE_N];

    const int t    = threadIdx.x;
    const int bid  = blockIdx.x;        // 0..511
    const int half = bid & 1;           // which 16-row half of the image
    const int bf   = bid >> 1;          // = b*NF + f
    const int f    = bf & (NF - 1);
    const int bb   = bf >> 5;           // / NF
    const int xx   = t & 31;            // output column
    const int y0   = half * 16 + ((t >> 5) << 1); // first of 2 output rows

    // c-invariant staging geometry: element idx = t + i*256 of the 34x34 tile
    int  soff[5];
    bool svalid[5];
#pragma unroll
    for (int i = 0; i < 5; ++i) {
        int idx = t + i * 256;
        int ry  = idx / TS;
        int rx  = idx - ry * TS;
        bool ok = (idx < TILE_N) && (ry >= 1) && (ry <= NH) && (rx >= 1) && (rx <= NW);
        svalid[i] = ok;
        soff[i]   = ok ? ((ry - 1) * NW + (rx - 1)) : 0; // clamped: always in-bounds
    }

    const float* __restrict__ xb    = x    + (size_t)bb * NC * NH * NW;
    const float* __restrict__ abase = nums + (size_t)f * NQ * NC * 6;
    const float* __restrict__ bbase = dens + (size_t)f * NQ * NC * 4;

    // prefetch channel 0 into registers
    float st[5];
#pragma unroll
    for (int i = 0; i < 5; ++i)
        st[i] = xb[soff[i]];

    float acc0 = 0.f, acc1 = 0.f;

    for (int c = 0; c < NC; ++c) {
        float* tl = tile[c & 1];

        // write staged channel c (zero-padded) to LDS
#pragma unroll
        for (int i = 0; i < 5; ++i) {
            int idx = t + i * 256;
            if (idx < TILE_N)
                tl[idx] = svalid[i] ? st[i] : 0.f;
        }
        // prefetch channel c+1 (latency hidden behind compute below)
        if (c + 1 < NC) {
            const float* xc = xb + (size_t)(c + 1) * NH * NW;
#pragma unroll
            for (int i = 0; i < 5; ++i)
                st[i] = xc[soff[i]];
        }
        __syncthreads(); // double-buffered: single barrier per channel suffices

        // 4x3 neighborhood covering both pixels' 3x3 windows.
        // padded coords: window value for pixel (y,x), pos (qi,qj) = tl[(y+qi)*TS + (x+qj)]
        float n[4][3];
#pragma unroll
        for (int dy = 0; dy < 4; ++dy)
#pragma unroll
            for (int dx = 0; dx < 3; ++dx)
                n[dy][dx] = tl[(y0 + dy) * TS + (xx + dx)];

#pragma unroll
        for (int q = 0; q < NQ; ++q) {
            // block-uniform coefficient loads -> s_load_dwordx*
            const float* ap = abase + (size_t)(q * NC + c) * 6;
            const float* bp = bbase + (size_t)(q * NC + c) * 4;
            const float a0 = ap[0], a1 = ap[1], a2 = ap[2],
                        a3 = ap[3], a4 = ap[4], a5 = ap[5];
            const float d0 = bp[0], d1 = bp[1], d2 = bp[2], d3 = bp[3];
            const int qi = q / 3, qj = q - qi * 3;

            {
                const float w  = n[qi][qj];
                float nu = fmaf(fmaf(fmaf(fmaf(fmaf(a5, w, a4), w, a3), w, a2), w, a1), w, a0);
                float dp = fmaf(fmaf(fmaf(d3, w, d2), w, d1), w, d0) * w;
                float de = 1.0f + fabsf(dp);
                acc0 = fmaf(nu, __builtin_amdgcn_rcpf(de), acc0);
            }
            {
                const float w  = n[qi + 1][qj];
                float nu = fmaf(fmaf(fmaf(fmaf(fmaf(a5, w, a4), w, a3), w, a2), w, a1), w, a0);
                float dp = fmaf(fmaf(fmaf(d3, w, d2), w, d1), w, d0) * w;
                float de = 1.0f + fabsf(dp);
                acc1 = fmaf(nu, __builtin_amdgcn_rcpf(de), acc1);
            }
        }
        // no trailing barrier needed: next iteration writes the OTHER buffer,
        // and buffer (c&1) is only rewritten at c+2, after barrier(c+1).
    }

    float* op = out + ((size_t)bf * NH + y0) * NW + xx;
    op[0]  = acc0;
    op[NW] = acc1;
}

extern "C" void kernel_launch(void* const* d_in, const int* in_sizes, int n_in,
                              void* d_out, int out_size, void* d_ws, size_t ws_size,
                              hipStream_t stream) {
    const float* x    = (const float*)d_in[0];
    const float* nums = (const float*)d_in[1];
    const float* dens = (const float*)d_in[2];
    float* out = (float*)d_out;

    dim3 grid(NB * NF * 2); // 512 blocks: (b, f, half)
    dim3 block(256);
    ka_conv_rational_kernel<<<grid, block, 0, stream>>>(x, nums, dens, out);
}

// Round 2
// 82.042 us; speedup vs baseline: 1.1751x; 1.1751x over previous
//
#include <hip/hip_runtime.h>
#include <math.h>

// Problem constants (from reference): B=8, C=32, F=32, K=3, H=W=32
#define NB 8
#define NC 32
#define NF 32
#define NH 32
#define NW 32
#define NQ 9
#define CSPLIT 4            // channel-loop split factor (8 channels per block)
#define CPB (NC / CSPLIT)   // channels per block
#define TROWS 18            // staged padded rows per half-image (16 + 2 halo)
#define TS 34               // padded tile row stride (W+2)
#define TILE_N (TROWS * TS) // 612

typedef float f2 __attribute__((ext_vector_type(2)));
__device__ __forceinline__ f2 sp(float v) { return (f2){v, v}; }

// Block = 256 threads, each owns 2 vertically-adjacent output pixels
// (16 rows x 32 cols = half image). Grid = B*F*2 halves * CSPLIT = 2048
// -> 8 blocks/CU -> 32 waves/CU. Coefficients are block-uniform -> SGPRs.
// Channel partials combined with HW fp32 atomics (out pre-zeroed).
__global__ __launch_bounds__(256, 8) void ka_conv_rational_kernel(
    const float* __restrict__ x,     // [B, C, H, W]
    const float* __restrict__ nums,  // [F*Q*C, 6]
    const float* __restrict__ dens,  // [F*Q*C, 4]
    float* __restrict__ out)         // [B, F, H, W]
{
    __shared__ float tile[2][TILE_N];

    const int t    = threadIdx.x;
    const int bid  = blockIdx.x;          // 0..2047
    const int cs   = bid & (CSPLIT - 1);  // channel chunk
    const int half = (bid >> 2) & 1;      // which 16-row half of the image
    const int bf   = bid >> 3;            // = b*NF + f, 0..255
    const int f    = bf & (NF - 1);
    const int bb   = bf >> 5;             // / NF
    const int xx   = t & 31;              // output column
    const int ty   = t >> 5;              // 0..7 -> owns rows 2*ty, 2*ty+1 of the half
    const int c0   = cs * CPB;

    // c-invariant staging geometry: element idx of the 18x34 padded tile.
    // padded row (global) = half*16 + ry  ->  unpadded gy = half*16 + ry - 1
    int  soff[3];
    bool svalid[3];
#pragma unroll
    for (int i = 0; i < 3; ++i) {
        int idx = t + i * 256;
        int ry  = idx / TS;
        int rx  = idx - ry * TS;
        int gy  = half * 16 + ry - 1;
        int gx  = rx - 1;
        bool ok = (idx < TILE_N) && (gy >= 0) && (gy < NH) && (gx >= 0) && (gx < NW);
        svalid[i] = ok;
        soff[i]   = ok ? (gy * NW + gx) : 0; // clamped: always in-bounds
    }

    const float* __restrict__ xb    = x    + ((size_t)bb * NC + c0) * NH * NW;
    const float* __restrict__ abase = nums + (size_t)f * NQ * NC * 6;
    const float* __restrict__ bbase = dens + (size_t)f * NQ * NC * 4;

    // prefetch first channel into registers
    float st[3];
#pragma unroll
    for (int i = 0; i < 3; ++i)
        st[i] = xb[soff[i]];

    f2 acc = {0.f, 0.f};

    for (int ci = 0; ci < CPB; ++ci) {
        const int c = c0 + ci;
        float* tl = tile[ci & 1];

        // write staged channel (zero-padded) to LDS
#pragma unroll
        for (int i = 0; i < 3; ++i) {
            int idx = t + i * 256;
            if (idx < TILE_N)
                tl[idx] = svalid[i] ? st[i] : 0.f;
        }
        // prefetch next channel (latency hidden behind compute below)
        if (ci + 1 < CPB) {
            const float* xc = xb + (size_t)(ci + 1) * NH * NW;
#pragma unroll
            for (int i = 0; i < 3; ++i)
                st[i] = xc[soff[i]];
        }
        __syncthreads(); // double-buffered: buffer (ci&1) next rewritten at ci+2

        // 4x3 neighborhood covering both pixels' 3x3 windows
        float n[4][3];
#pragma unroll
        for (int dy = 0; dy < 4; ++dy)
#pragma unroll
            for (int dx = 0; dx < 3; ++dx)
                n[dy][dx] = tl[(ty * 2 + dy) * TS + (xx + dx)];

#pragma unroll
        for (int q = 0; q < NQ; ++q) {
            // block-uniform coefficient loads -> scalar loads
            const float* ap = abase + (size_t)(q * NC + c) * 6;
            const float* bp = bbase + (size_t)(q * NC + c) * 4;
            const float a0 = ap[0], a1 = ap[1], a2 = ap[2],
                        a3 = ap[3], a4 = ap[4], a5 = ap[5];
            const float d0 = bp[0], d1 = bp[1], d2 = bp[2], d3 = bp[3];
            const int qi = q / 3, qj = q - qi * 3;

            // both pixels' terms evaluated as <2 x float> (v_pk_* candidates)
            f2 w = {n[qi][qj], n[qi + 1][qj]};
            f2 nu = __builtin_elementwise_fma(sp(a5), w, sp(a4));
            nu = __builtin_elementwise_fma(nu, w, sp(a3));
            nu = __builtin_elementwise_fma(nu, w, sp(a2));
            nu = __builtin_elementwise_fma(nu, w, sp(a1));
            nu = __builtin_elementwise_fma(nu, w, sp(a0));
            f2 dp = __builtin_elementwise_fma(sp(d3), w, sp(d2));
            dp = __builtin_elementwise_fma(dp, w, sp(d1));
            dp = __builtin_elementwise_fma(dp, w, sp(d0));
            dp = dp * w;
            f2 de = 1.0f + __builtin_elementwise_abs(dp);
            f2 r  = {__builtin_amdgcn_rcpf(de.x), __builtin_amdgcn_rcpf(de.y)};
            acc = __builtin_elementwise_fma(nu, r, acc);
        }
    }

    const int y0 = half * 16 + ty * 2;
    float* op = out + ((size_t)bf * NH + y0) * NW + xx;
    unsafeAtomicAdd(op, acc.x);
    unsafeAtomicAdd(op + NW, acc.y);
}

extern "C" void kernel_launch(void* const* d_in, const int* in_sizes, int n_in,
                              void* d_out, int out_size, void* d_ws, size_t ws_size,
                              hipStream_t stream) {
    const float* x    = (const float*)d_in[0];
    const float* nums = (const float*)d_in[1];
    const float* dens = (const float*)d_in[2];
    float* out = (float*)d_out;

    // atomic accumulation target must start at zero (harness poisons d_out)
    hipMemsetAsync(d_out, 0, (size_t)out_size * sizeof(float), stream);

    dim3 grid(NB * NF * 2 * CSPLIT); // 2048 blocks: (b, f, half, csplit)
    dim3 block(256);
    ka_conv_rational_kernel<<<grid, block, 0, stream>>>(x, nums, dens, out);
}